// Round 1
// baseline (494.544 us; speedup 1.0000x reference)
//
#include <hip/hip_runtime.h>

typedef unsigned short u16;
typedef __attribute__((ext_vector_type(8))) __bf16 bf16x8;
typedef __attribute__((ext_vector_type(4))) float floatx4;

__device__ __forceinline__ u16 f2bf(float f) {
    unsigned u = __float_as_uint(f);
    unsigned r = (u + 0x7FFFu + ((u >> 16) & 1u)) >> 16;
    return (u16)r;
}
__device__ __forceinline__ float bf2f(u16 v) {
    return __uint_as_float(((unsigned)v) << 16);
}

__device__ __forceinline__ void load_lds16(const void* g, void* l) {
    __builtin_amdgcn_global_load_lds(
        (const __attribute__((address_space(1))) void*)g,
        (__attribute__((address_space(3))) void*)l, 16, 0, 0);
}

// ---------------------------------------------------------------------------
// cast fp32 -> bf16, flat, n multiple of 4
__global__ __launch_bounds__(256) void cast_bf16(const float* __restrict__ in,
                                                 u16* __restrict__ out, long n) {
    long i = ((long)blockIdx.x * 256 + threadIdx.x) * 4;
    if (i < n) {
        float4 v = *(const float4*)(in + i);
        ushort4 o;
        o.x = f2bf(v.x); o.y = f2bf(v.y); o.z = f2bf(v.z); o.w = f2bf(v.w);
        *(ushort4*)(out + i) = o;
    }
}

// transpose + cast: out[i][j] = bf16(in[j][i]), HxH, block (32,8), grid (H/32,H/32)
__global__ __launch_bounds__(256) void transpose_cast(const float* __restrict__ in,
                                                      u16* __restrict__ out, int H) {
    __shared__ float t[32][33];
    int bx = blockIdx.x * 32, by = blockIdx.y * 32;
    int x = threadIdx.x;
    for (int y = threadIdx.y; y < 32; y += 8)
        t[y][x] = in[(size_t)(by + y) * H + bx + x];
    __syncthreads();
    for (int y = threadIdx.y; y < 32; y += 8)
        out[(size_t)(bx + y) * H + by + x] = f2bf(t[x][y]);
}

// u_q[h] = sum_o Wq[o,h]*bk[o]   (z=0), u_k[h] = sum_o Wk[o,h]*bq[o] (z=1)
// grid (H/256, 16, 2); u must be zeroed first (atomicAdd).
__global__ __launch_bounds__(256) void vecmat_u(const float* __restrict__ Wq,
                                                const float* __restrict__ bk,
                                                const float* __restrict__ Wk,
                                                const float* __restrict__ bq,
                                                float* __restrict__ u, int H) {
    const float* W = blockIdx.z ? Wk : Wq;
    const float* b = blockIdx.z ? bq : bk;
    float* out = u + (size_t)blockIdx.z * H;
    int h = blockIdx.x * 256 + threadIdx.x;
    int chunk = H / 16;
    int o0 = blockIdx.y * chunk;
    float s = 0.f;
    for (int o = o0; o < o0 + chunk; ++o) s += b[o] * W[(size_t)o * H + h];
    atomicAdd(&out[h], s);
}

// c[j] = sum_o Wo[j,o]*bv[o] + bo[j]  (blocks 0..H-1);  block H: d = sum bq*bk
__global__ __launch_bounds__(256) void bias_c(const float* __restrict__ Wo,
                                              const float* __restrict__ bv,
                                              const float* __restrict__ bo,
                                              const float* __restrict__ bq,
                                              const float* __restrict__ bk,
                                              float* __restrict__ c,
                                              float* __restrict__ dsc, int H) {
    __shared__ float red[4];
    int j = blockIdx.x;
    int lane = threadIdx.x & 63, wv = threadIdx.x >> 6;
    float s = 0.f;
    if (j < H) {
        for (int o = threadIdx.x; o < H; o += 256) s += Wo[(size_t)j * H + o] * bv[o];
    } else {
        for (int o = threadIdx.x; o < H; o += 256) s += bq[o] * bk[o];
    }
    for (int off = 32; off > 0; off >>= 1) s += __shfl_down(s, off);
    if (lane == 0) red[wv] = s;
    __syncthreads();
    if (threadIdx.x == 0) {
        float t = red[0] + red[1] + red[2] + red[3];
        if (j < H) c[j] = t + bo[j];
        else *dsc = t;
    }
}

// ---------------------------------------------------------------------------
// BT-GEMM: C[i,j] = sum_k A[i,k]*Bw[j,k] (+bias[j]).  A:[M,K] Bw:[N,K] bf16.
// 128x128 tile, BK=32, 256 threads (4 waves), each wave a 64x64 quadrant.
template <int OUTB>
__global__ __launch_bounds__(256) void gemm_bt(const u16* __restrict__ A,
                                               const u16* __restrict__ Bw,
                                               u16* __restrict__ Cb,
                                               float* __restrict__ Cf,
                                               const float* __restrict__ bias,
                                               int M, int N, int K) {
    __shared__ __align__(16) u16 As[128 * 32];
    __shared__ __align__(16) u16 Bs[128 * 32];
    const int tid = threadIdx.x, lane = tid & 63, wv = tid >> 6;
    const int m0 = blockIdx.x * 128, n0 = blockIdx.y * 128;
    const int wm = (wv >> 1) * 64, wn = (wv & 1) * 64;

    floatx4 acc[4][4];
#pragma unroll
    for (int i = 0; i < 4; ++i)
#pragma unroll
        for (int j = 0; j < 4; ++j) acc[i][j] = (floatx4){0.f, 0.f, 0.f, 0.f};

    const int srow = lane >> 2, scol = (lane & 3) * 8;
    const u16* gA = A + (size_t)(m0 + srow) * K + scol;
    const u16* gB = Bw + (size_t)(n0 + srow) * K + scol;
    const int r = lane & 15, q = lane >> 4;

    for (int kt = 0; kt < K; kt += 32) {
#pragma unroll
        for (int c = 0; c < 2; ++c) {
            int chunk = wv * 2 + c;
            load_lds16(gA + (size_t)(chunk * 16) * K + kt, &As[chunk * 16 * 32]);
            load_lds16(gB + (size_t)(chunk * 16) * K + kt, &Bs[chunk * 16 * 32]);
        }
        __syncthreads();
        bf16x8 af[4], bfr[4];
#pragma unroll
        for (int i = 0; i < 4; ++i) {
            af[i] = *(const bf16x8*)&As[(wm + i * 16 + r) * 32 + q * 8];
            bfr[i] = *(const bf16x8*)&Bs[(wn + i * 16 + r) * 32 + q * 8];
        }
#pragma unroll
        for (int i = 0; i < 4; ++i)
#pragma unroll
            for (int j = 0; j < 4; ++j)
                acc[i][j] = __builtin_amdgcn_mfma_f32_16x16x32_bf16(af[i], bfr[j], acc[i][j], 0, 0, 0);
        __syncthreads();
    }

    const int cc = lane & 15, cr = (lane >> 4) * 4;
#pragma unroll
    for (int i = 0; i < 4; ++i)
#pragma unroll
        for (int j = 0; j < 4; ++j) {
            int col = n0 + wn + j * 16 + cc;
            float badd = bias ? bias[col] : 0.f;
#pragma unroll
            for (int r0 = 0; r0 < 4; ++r0) {
                int row = m0 + wm + i * 16 + cr + r0;
                float v = acc[i][j][r0] + badd;
                if (OUTB) Cb[(size_t)row * N + col] = f2bf(v);
                else Cf[(size_t)row * N + col] = v;
            }
        }
}

// ---------------------------------------------------------------------------
// Per-batch attention: scores -> softmax -> w[4] -> Y = sum_n w[n]*x[n,:]
__global__ __launch_bounds__(256) void attn_fuse(const u16* __restrict__ G,
                                                 const u16* __restrict__ X,
                                                 const float* __restrict__ conf,
                                                 const float* __restrict__ u,
                                                 const float* __restrict__ dsc,
                                                 u16* __restrict__ Y, int H) {
    const int b = blockIdx.x;
    const int tid = threadIdx.x, lane = tid & 63, wv = tid >> 6;
    const u16* Gb = G + (size_t)b * 4 * H;
    const u16* Xb = X + (size_t)b * 4 * H;

    float vals[24];
#pragma unroll
    for (int t = 0; t < 24; ++t) vals[t] = 0.f;

    for (int h = tid; h < H; h += 256) {
        float xv[4], gv[4];
#pragma unroll
        for (int n = 0; n < 4; ++n) xv[n] = bf2f(Xb[n * H + h]);
#pragma unroll
        for (int m = 0; m < 4; ++m) gv[m] = bf2f(Gb[m * H + h]);
        float uq = u[h], uk = u[H + h];
#pragma unroll
        for (int m = 0; m < 4; ++m) {
            vals[16 + m] += xv[m] * uq;
            vals[20 + m] += xv[m] * uk;
#pragma unroll
            for (int n = 0; n < 4; ++n) vals[m * 4 + n] += gv[m] * xv[n];
        }
    }
#pragma unroll
    for (int t = 0; t < 24; ++t) {
        float v = vals[t];
        for (int off = 32; off > 0; off >>= 1) v += __shfl_down(v, off);
        vals[t] = v;
    }
    __shared__ float red[4][24];
    __shared__ float wsh[4];
    if (lane == 0)
#pragma unroll
        for (int t = 0; t < 24; ++t) red[wv][t] = vals[t];
    __syncthreads();
    if (tid == 0) {
        float s[24];
#pragma unroll
        for (int t = 0; t < 24; ++t) s[t] = red[0][t] + red[1][t] + red[2][t] + red[3][t];
        float d = *dsc;
        float w[4] = {0.f, 0.f, 0.f, 0.f};
#pragma unroll
        for (int m = 0; m < 4; ++m) {
            float cm = conf[(size_t)b * 4 + m];
            float sc[4], mx = -1e30f;
#pragma unroll
            for (int n = 0; n < 4; ++n) {
                sc[n] = (s[m * 4 + n] + s[16 + m] + s[20 + n] + d) * 0.03125f * cm;
                mx = fmaxf(mx, sc[n]);
            }
            float e[4], ssum = 0.f;
#pragma unroll
            for (int n = 0; n < 4; ++n) { e[n] = __expf(sc[n] - mx); ssum += e[n]; }
            float inv = 0.25f / ssum;
#pragma unroll
            for (int n = 0; n < 4; ++n) w[n] += e[n] * inv;
        }
#pragma unroll
        for (int n = 0; n < 4; ++n) wsh[n] = w[n];
    }
    __syncthreads();
    float w0 = wsh[0], w1 = wsh[1], w2 = wsh[2], w3 = wsh[3];
    for (int h = tid; h < H; h += 256) {
        float y = w0 * bf2f(Xb[h]) + w1 * bf2f(Xb[H + h]) +
                  w2 * bf2f(Xb[2 * H + h]) + w3 * bf2f(Xb[3 * H + h]);
        Y[(size_t)b * H + h] = f2bf(y);
    }
}

// ---------------------------------------------------------------------------
extern "C" void kernel_launch(void* const* d_in, const int* in_sizes, int n_in,
                              void* d_out, int out_size, void* d_ws, size_t ws_size,
                              hipStream_t stream) {
    const int H = 1024, M = 4;
    const int B = in_sizes[0] / (H * M);
    const long BMH = (long)B * M * H;

    const float* feat = (const float*)d_in[0];
    const float* conf = (const float*)d_in[1];
    const float* Wq = (const float*)d_in[2];
    const float* bq = (const float*)d_in[3];
    const float* Wk = (const float*)d_in[4];
    const float* bk = (const float*)d_in[5];
    const float* Wv = (const float*)d_in[6];
    const float* bv = (const float*)d_in[7];
    const float* Wo = (const float*)d_in[8];
    const float* bo = (const float*)d_in[9];

    char* ws = (char*)d_ws;
    size_t off = 0;
    auto alloc = [&](size_t bytes) {
        void* p = ws + off;
        off += (bytes + 255) & ~(size_t)255;
        return p;
    };
    u16* Xb   = (u16*)alloc((size_t)BMH * 2);
    u16* G    = (u16*)alloc((size_t)BMH * 2);
    u16* Yb   = (u16*)alloc((size_t)B * H * 2);
    u16* WkT  = (u16*)alloc((size_t)H * H * 2);
    u16* WqT  = (u16*)alloc((size_t)H * H * 2);
    u16* WvT  = (u16*)alloc((size_t)H * H * 2);
    u16* Wob  = (u16*)alloc((size_t)H * H * 2);
    u16* Aw   = (u16*)alloc((size_t)H * H * 2);
    u16* Wov  = (u16*)alloc((size_t)H * H * 2);
    float* u    = (float*)alloc((size_t)2 * H * 4);
    float* cvec = (float*)alloc((size_t)H * 4);
    float* dsc  = (float*)alloc(256);
    (void)ws_size; (void)n_in; (void)out_size;

    // 1. casts
    cast_bf16<<<(int)(BMH / 4 / 256), 256, 0, stream>>>(feat, Xb, BMH);
    cast_bf16<<<H * H / 4 / 256, 256, 0, stream>>>(Wo, Wob, (long)H * H);
    dim3 tb(32, 8), tg(H / 32, H / 32);
    transpose_cast<<<tg, tb, 0, stream>>>(Wk, WkT, H);
    transpose_cast<<<tg, tb, 0, stream>>>(Wq, WqT, H);
    transpose_cast<<<tg, tb, 0, stream>>>(Wv, WvT, H);

    // 2. small bias-derived vectors
    hipMemsetAsync(u, 0, (size_t)2 * H * 4, stream);
    vecmat_u<<<dim3(H / 256, 16, 2), 256, 0, stream>>>(Wq, bk, Wk, bq, u, H);
    bias_c<<<H + 1, 256, 0, stream>>>(Wo, bv, bo, bq, bk, cvec, dsc, H);

    // 3. weight-product GEMMs: Aw[i,j] = sum_o Wk[o,i]Wq[o,j]; Wov[j,h] = sum_o Wo[j,o]Wv[o,h]
    gemm_bt<1><<<dim3(H / 128, H / 128), 256, 0, stream>>>(WkT, WqT, Aw, nullptr, nullptr, H, H, H);
    gemm_bt<1><<<dim3(H / 128, H / 128), 256, 0, stream>>>(Wob, WvT, Wov, nullptr, nullptr, H, H, H);

    // 4. big GEMM: G[r,h'] = sum_h Xb[r,h] * Aw[h',h]
    gemm_bt<1><<<dim3(B * M / 128, H / 128), 256, 0, stream>>>(Xb, Aw, G, nullptr, nullptr, B * M, H, H);

    // 5. attention -> Y
    attn_fuse<<<B, 256, 0, stream>>>(G, Xb, conf, u, dsc, Yb, H);

    // 6. out = Y @ Wov^T + cvec
    gemm_bt<0><<<dim3(B / 128, H / 128), 256, 0, stream>>>(Yb, Wov, nullptr, (float*)d_out, cvec, B, H, H);
}

// Round 2
// 420.302 us; speedup vs baseline: 1.1766x; 1.1766x over previous
//
#include <hip/hip_runtime.h>

typedef unsigned short u16;
typedef __attribute__((ext_vector_type(8))) __bf16 bf16x8;
typedef __attribute__((ext_vector_type(4))) float floatx4;

__device__ __forceinline__ u16 f2bf(float f) {
    unsigned u = __float_as_uint(f);
    unsigned r = (u + 0x7FFFu + ((u >> 16) & 1u)) >> 16;
    return (u16)r;
}
__device__ __forceinline__ float bf2f(u16 v) {
    return __uint_as_float(((unsigned)v) << 16);
}

__device__ __forceinline__ void load_lds16(const void* g, void* l) {
    __builtin_amdgcn_global_load_lds(
        (const __attribute__((address_space(1))) void*)g,
        (__attribute__((address_space(3))) void*)l, 16, 0, 0);
}

// unpack 8 bf16 (packed in uint4) -> 8 floats
__device__ __forceinline__ void unpack8(uint4 v, float* f) {
    f[0] = __uint_as_float(v.x << 16);
    f[1] = __uint_as_float(v.x & 0xFFFF0000u);
    f[2] = __uint_as_float(v.y << 16);
    f[3] = __uint_as_float(v.y & 0xFFFF0000u);
    f[4] = __uint_as_float(v.z << 16);
    f[5] = __uint_as_float(v.z & 0xFFFF0000u);
    f[6] = __uint_as_float(v.w << 16);
    f[7] = __uint_as_float(v.w & 0xFFFF0000u);
}

// ---------------------------------------------------------------------------
// cast fp32 -> bf16, flat, n multiple of 4
__global__ __launch_bounds__(256) void cast_bf16(const float* __restrict__ in,
                                                 u16* __restrict__ out, long n) {
    long i = ((long)blockIdx.x * 256 + threadIdx.x) * 4;
    if (i < n) {
        float4 v = *(const float4*)(in + i);
        ushort4 o;
        o.x = f2bf(v.x); o.y = f2bf(v.y); o.z = f2bf(v.z); o.w = f2bf(v.w);
        *(ushort4*)(out + i) = o;
    }
}

// z=0: WkT=Wk^T, z=1: WqT=Wq^T, z=2: WvT=Wv^T (transpose+cast); z=3: Wob=cast(Wo)
// block (32,8), grid (H/32, H/32, 4)
__global__ __launch_bounds__(256) void prep_weights(const float* __restrict__ Wq,
                                                    const float* __restrict__ Wk,
                                                    const float* __restrict__ Wv,
                                                    const float* __restrict__ Wo,
                                                    u16* __restrict__ WqT,
                                                    u16* __restrict__ WkT,
                                                    u16* __restrict__ WvT,
                                                    u16* __restrict__ Wob, int H) {
    __shared__ float t[32][33];
    const int z = blockIdx.z;
    const float* in = (z == 0) ? Wk : (z == 1) ? Wq : (z == 2) ? Wv : Wo;
    u16* out = (z == 0) ? WkT : (z == 1) ? WqT : (z == 2) ? WvT : Wob;
    int bx = blockIdx.x * 32, by = blockIdx.y * 32;
    int x = threadIdx.x;
    if (z < 3) {
        for (int y = threadIdx.y; y < 32; y += 8)
            t[y][x] = in[(size_t)(by + y) * H + bx + x];
        __syncthreads();
        for (int y = threadIdx.y; y < 32; y += 8)
            out[(size_t)(bx + y) * H + by + x] = f2bf(t[x][y]);
    } else {
        for (int y = threadIdx.y; y < 32; y += 8)
            out[(size_t)(by + y) * H + bx + x] = f2bf(in[(size_t)(by + y) * H + bx + x]);
    }
}

// uk[h] = sum_o Wk[o,h]*bq[o]; grid (H/256, 16); u zeroed first (atomicAdd).
__global__ __launch_bounds__(256) void vecmat_u(const float* __restrict__ Wk,
                                                const float* __restrict__ bq,
                                                float* __restrict__ u, int H) {
    int h = blockIdx.x * 256 + threadIdx.x;
    int chunk = H / 16;
    int o0 = blockIdx.y * chunk;
    float s = 0.f;
    for (int o = o0; o < o0 + chunk; ++o) s += bq[o] * Wk[(size_t)o * H + h];
    atomicAdd(&u[h], s);
}

// c[j] = sum_o Wo[j,o]*bv[o] + bo[j]
__global__ __launch_bounds__(256) void bias_c(const float* __restrict__ Wo,
                                              const float* __restrict__ bv,
                                              const float* __restrict__ bo,
                                              float* __restrict__ c, int H) {
    __shared__ float red[4];
    int j = blockIdx.x;
    int lane = threadIdx.x & 63, wv = threadIdx.x >> 6;
    float s = 0.f;
    for (int o = threadIdx.x; o < H; o += 256) s += Wo[(size_t)j * H + o] * bv[o];
    for (int off = 32; off > 0; off >>= 1) s += __shfl_down(s, off);
    if (lane == 0) red[wv] = s;
    __syncthreads();
    if (threadIdx.x == 0) c[j] = red[0] + red[1] + red[2] + red[3] + bo[j];
}

// ---------------------------------------------------------------------------
// BT-GEMM body: C[i,j] = sum_k A[i,k]*Bw[j,k] (+bias[j]).  A:[M,K] Bw:[N,K] bf16.
// 128x128 tile, BK=32, 256 threads (4 waves), each wave a 64x64 quadrant.
// LDS XOR swizzle: physical 16B-chunk c_phys = c_log ^ ((row>>1)&3) kills the
// 8-lane bank-group aliasing of the naive layout (2 lanes/bank-group = free).
template <int OUTB>
__device__ __forceinline__ void gemm_body(const u16* __restrict__ A,
                                          const u16* __restrict__ Bw,
                                          u16* __restrict__ Cb,
                                          float* __restrict__ Cf,
                                          const float* __restrict__ bias,
                                          int M, int N, int K,
                                          int bx, int by) {
    __shared__ __align__(16) u16 As[128 * 32];
    __shared__ __align__(16) u16 Bs[128 * 32];
    const int tid = threadIdx.x, lane = tid & 63, wv = tid >> 6;
    const int m0 = bx * 128, n0 = by * 128;
    const int wm = (wv >> 1) * 64, wn = (wv & 1) * 64;

    floatx4 acc[4][4];
#pragma unroll
    for (int i = 0; i < 4; ++i)
#pragma unroll
        for (int j = 0; j < 4; ++j) acc[i][j] = (floatx4){0.f, 0.f, 0.f, 0.f};

    const int srow = lane >> 2;
    const int scol = (((lane & 3) ^ ((lane >> 3) & 3)) * 8);  // swizzled source chunk
    const u16* gA = A + (size_t)(m0 + srow) * K + scol;
    const u16* gB = Bw + (size_t)(n0 + srow) * K + scol;
    const int r = lane & 15, q = lane >> 4;
    const int cph = q ^ ((r >> 1) & 3);  // reader-side physical chunk

    for (int kt = 0; kt < K; kt += 32) {
#pragma unroll
        for (int c = 0; c < 2; ++c) {
            int chunk = wv * 2 + c;
            load_lds16(gA + (size_t)(chunk * 16) * K + kt, &As[chunk * 16 * 32]);
            load_lds16(gB + (size_t)(chunk * 16) * K + kt, &Bs[chunk * 16 * 32]);
        }
        __syncthreads();
        bf16x8 af[4], bfr[4];
#pragma unroll
        for (int i = 0; i < 4; ++i) {
            af[i] = *(const bf16x8*)&As[(wm + i * 16 + r) * 32 + cph * 8];
            bfr[i] = *(const bf16x8*)&Bs[(wn + i * 16 + r) * 32 + cph * 8];
        }
#pragma unroll
        for (int i = 0; i < 4; ++i)
#pragma unroll
            for (int j = 0; j < 4; ++j)
                acc[i][j] = __builtin_amdgcn_mfma_f32_16x16x32_bf16(af[i], bfr[j], acc[i][j], 0, 0, 0);
        __syncthreads();
    }

    const int cc = lane & 15, cr = (lane >> 4) * 4;
#pragma unroll
    for (int i = 0; i < 4; ++i)
#pragma unroll
        for (int j = 0; j < 4; ++j) {
            int col = n0 + wn + j * 16 + cc;
            float badd = bias ? bias[col] : 0.f;
#pragma unroll
            for (int r0 = 0; r0 < 4; ++r0) {
                int row = m0 + wm + i * 16 + cr + r0;
                float v = acc[i][j][r0] + badd;
                if (OUTB) Cb[(size_t)row * N + col] = f2bf(v);
                else Cf[(size_t)row * N + col] = v;
            }
        }
}

template <int OUTB>
__global__ __launch_bounds__(256) void gemm_bt(const u16* __restrict__ A,
                                               const u16* __restrict__ Bw,
                                               u16* __restrict__ Cb,
                                               float* __restrict__ Cf,
                                               const float* __restrict__ bias,
                                               int M, int N, int K) {
    gemm_body<OUTB>(A, Bw, Cb, Cf, bias, M, N, K, blockIdx.x, blockIdx.y);
}

// two HxH weight GEMMs in one launch (z selects); both bf16-out, no bias
__global__ __launch_bounds__(256) void gemm_bt_dual(const u16* __restrict__ A0,
                                                    const u16* __restrict__ B0,
                                                    u16* __restrict__ C0,
                                                    const u16* __restrict__ A1,
                                                    const u16* __restrict__ B1,
                                                    u16* __restrict__ C1, int H) {
    if (blockIdx.z == 0)
        gemm_body<1>(A0, B0, C0, nullptr, nullptr, H, H, H, blockIdx.x, blockIdx.y);
    else
        gemm_body<1>(A1, B1, C1, nullptr, nullptr, H, H, H, blockIdx.x, blockIdx.y);
}

// ---------------------------------------------------------------------------
// Per-batch attention. One WAVE per batch, block=256 -> 4 batches/block.
// G' rows already include the uk bias (folded into big GEMM); the remaining
// n-constant score terms cancel in softmax. s[m][n] = G'_m . X_n.
__global__ __launch_bounds__(256) void attn_fuse(const u16* __restrict__ G,
                                                 const u16* __restrict__ X,
                                                 const float* __restrict__ conf,
                                                 u16* __restrict__ Y, int H) {
    const int lane = threadIdx.x & 63, wv = threadIdx.x >> 6;
    const int b = blockIdx.x * 4 + wv;
    const u16* Gb = G + (size_t)b * 4 * H;
    const u16* Xb = X + (size_t)b * 4 * H;

    float s[16];
#pragma unroll
    for (int t = 0; t < 16; ++t) s[t] = 0.f;

#pragma unroll
    for (int c = 0; c < 2; ++c) {
        const int off = c * 512 + lane * 8;
        float xv[4][8], gv[4][8];
#pragma unroll
        for (int rr = 0; rr < 4; ++rr) {
            uint4 xl = *(const uint4*)(Xb + rr * H + off);
            uint4 gl = *(const uint4*)(Gb + rr * H + off);
            unpack8(xl, xv[rr]);
            unpack8(gl, gv[rr]);
        }
#pragma unroll
        for (int m = 0; m < 4; ++m)
#pragma unroll
            for (int n = 0; n < 4; ++n) {
                float a = 0.f;
#pragma unroll
                for (int j = 0; j < 8; ++j) a += gv[m][j] * xv[n][j];
                s[m * 4 + n] += a;
            }
    }
    // butterfly all-reduce: every lane ends with the full 16 sums
#pragma unroll
    for (int t = 0; t < 16; ++t) {
#pragma unroll
        for (int mask = 32; mask; mask >>= 1) s[t] += __shfl_xor(s[t], mask);
    }
    // redundant per-lane softmax -> fused weights w[4]
    float w[4] = {0.f, 0.f, 0.f, 0.f};
#pragma unroll
    for (int m = 0; m < 4; ++m) {
        float cm = conf[(size_t)b * 4 + m] * 0.03125f;
        float sc[4], mx = -1e30f;
#pragma unroll
        for (int n = 0; n < 4; ++n) {
            sc[n] = s[m * 4 + n] * cm;
            mx = fmaxf(mx, sc[n]);
        }
        float e[4], ssum = 0.f;
#pragma unroll
        for (int n = 0; n < 4; ++n) { e[n] = __expf(sc[n] - mx); ssum += e[n]; }
        float inv = 0.25f / ssum;
#pragma unroll
        for (int n = 0; n < 4; ++n) w[n] += e[n] * inv;
    }
    // Y = sum_n w[n] * X_n  (reload X chunks; L1/L2-resident)
#pragma unroll
    for (int c = 0; c < 2; ++c) {
        const int off = c * 512 + lane * 8;
        float xv[4][8];
#pragma unroll
        for (int rr = 0; rr < 4; ++rr) {
            uint4 xl = *(const uint4*)(Xb + rr * H + off);
            unpack8(xl, xv[rr]);
        }
        float y[8];
#pragma unroll
        for (int j = 0; j < 8; ++j)
            y[j] = w[0] * xv[0][j] + w[1] * xv[1][j] + w[2] * xv[2][j] + w[3] * xv[3][j];
        uint4 res;
        res.x = (unsigned)f2bf(y[0]) | ((unsigned)f2bf(y[1]) << 16);
        res.y = (unsigned)f2bf(y[2]) | ((unsigned)f2bf(y[3]) << 16);
        res.z = (unsigned)f2bf(y[4]) | ((unsigned)f2bf(y[5]) << 16);
        res.w = (unsigned)f2bf(y[6]) | ((unsigned)f2bf(y[7]) << 16);
        *(uint4*)(Y + (size_t)b * H + off) = res;
    }
}

// ---------------------------------------------------------------------------
extern "C" void kernel_launch(void* const* d_in, const int* in_sizes, int n_in,
                              void* d_out, int out_size, void* d_ws, size_t ws_size,
                              hipStream_t stream) {
    const int H = 1024, M = 4;
    const int B = in_sizes[0] / (H * M);
    const long BMH = (long)B * M * H;

    const float* feat = (const float*)d_in[0];
    const float* conf = (const float*)d_in[1];
    const float* Wq = (const float*)d_in[2];
    const float* bq = (const float*)d_in[3];
    const float* Wk = (const float*)d_in[4];
    const float* bv = (const float*)d_in[7];
    const float* Wv = (const float*)d_in[6];
    const float* Wo = (const float*)d_in[8];
    const float* bo = (const float*)d_in[9];

    char* ws = (char*)d_ws;
    size_t off = 0;
    auto alloc = [&](size_t bytes) {
        void* p = ws + off;
        off += (bytes + 255) & ~(size_t)255;
        return p;
    };
    u16* Xb   = (u16*)alloc((size_t)BMH * 2);
    u16* G    = (u16*)alloc((size_t)BMH * 2);
    u16* Yb   = (u16*)alloc((size_t)B * H * 2);
    u16* WkT  = (u16*)alloc((size_t)H * H * 2);
    u16* WqT  = (u16*)alloc((size_t)H * H * 2);
    u16* WvT  = (u16*)alloc((size_t)H * H * 2);
    u16* Wob  = (u16*)alloc((size_t)H * H * 2);
    u16* Aw   = (u16*)alloc((size_t)H * H * 2);
    u16* Wov  = (u16*)alloc((size_t)H * H * 2);
    float* u    = (float*)alloc((size_t)H * 4);
    float* cvec = (float*)alloc((size_t)H * 4);
    (void)ws_size; (void)n_in; (void)out_size;

    // 1. casts / transposes (one launch) + features cast
    cast_bf16<<<(int)(BMH / 4 / 256), 256, 0, stream>>>(feat, Xb, BMH);
    prep_weights<<<dim3(H / 32, H / 32, 4), dim3(32, 8), 0, stream>>>(
        Wq, Wk, Wv, Wo, WqT, WkT, WvT, Wob, H);

    // 2. bias-derived vectors: uk (score bias along h'), cvec (output bias)
    hipMemsetAsync(u, 0, (size_t)H * 4, stream);
    vecmat_u<<<dim3(H / 256, 16), 256, 0, stream>>>(Wk, (const float*)d_in[3], u, H);
    bias_c<<<H, 256, 0, stream>>>(Wo, bv, bo, cvec, H);
    (void)bq;

    // 3. weight-product GEMMs (one launch): Aw = Wk^T Wq ; Wov = Wo Wv
    gemm_bt_dual<<<dim3(H / 128, H / 128, 2), 256, 0, stream>>>(
        WkT, WqT, Aw, Wob, WvT, Wov, H);

    // 4. big GEMM: G[r,h'] = sum_h Xb[r,h] * Aw[h',h] + uk[h']
    gemm_bt<1><<<dim3(B * M / 128, H / 128), 256, 0, stream>>>(Xb, Aw, G, nullptr, u, B * M, H, H);

    // 5. attention -> Y (one wave per batch)
    attn_fuse<<<B / 4, 256, 0, stream>>>(G, Xb, conf, Yb, H);

    // 6. out = Y @ Wov^T + cvec
    gemm_bt<0><<<dim3(B / 128, H / 128), 256, 0, stream>>>(Yb, Wov, nullptr, (float*)d_out, cvec, B, H, H);
}

// Round 5
// 416.862 us; speedup vs baseline: 1.1864x; 1.0083x over previous
//
#include <hip/hip_runtime.h>

// WS BUDGET NOTE: R2 passed with ~156 MB of d_ws; R3/R4 (+32 MB Xf8, ~188 MB)
// failed with identical absmax across two different MFMA paths -> suspected
// ws_size overflow corrupting tail allocations. Keep total <= ~156 MB.

typedef unsigned short u16;
typedef __attribute__((ext_vector_type(8))) __bf16 bf16x8;
typedef __attribute__((ext_vector_type(4))) float floatx4;

__device__ __forceinline__ u16 f2bf(float f) {
    unsigned u = __float_as_uint(f);
    unsigned r = (u + 0x7FFFu + ((u >> 16) & 1u)) >> 16;
    return (u16)r;
}

__device__ __forceinline__ void load_lds16(const void* g, void* l) {
    __builtin_amdgcn_global_load_lds(
        (const __attribute__((address_space(1))) void*)g,
        (__attribute__((address_space(3))) void*)l, 16, 0, 0);
}

__device__ __forceinline__ void unpack8(uint4 v, float* f) {
    f[0] = __uint_as_float(v.x << 16);
    f[1] = __uint_as_float(v.x & 0xFFFF0000u);
    f[2] = __uint_as_float(v.y << 16);
    f[3] = __uint_as_float(v.y & 0xFFFF0000u);
    f[4] = __uint_as_float(v.z << 16);
    f[5] = __uint_as_float(v.z & 0xFFFF0000u);
    f[6] = __uint_as_float(v.w << 16);
    f[7] = __uint_as_float(v.w & 0xFFFF0000u);
}

// ---------------------------------------------------------------------------
// features fp32 -> bf16; 4 els/thread
__global__ __launch_bounds__(256) void k_cast(const float* __restrict__ in,
                                              u16* __restrict__ outb, long n) {
    long i = ((long)blockIdx.x * 256 + threadIdx.x) * 4;
    if (i < n) {
        float4 v = *(const float4*)(in + i);
        ushort4 o;
        o.x = f2bf(v.x); o.y = f2bf(v.y); o.z = f2bf(v.z); o.w = f2bf(v.w);
        *(ushort4*)(outb + i) = o;
    }
}

// z=0: WkT=Wk^T, z=1: WqT=Wq^T, z=2: WvT=Wv^T (transpose+cast); z=3: Wob=cast(Wo)
__global__ __launch_bounds__(256) void k_prep(const float* __restrict__ Wq,
                                              const float* __restrict__ Wk,
                                              const float* __restrict__ Wv,
                                              const float* __restrict__ Wo,
                                              u16* __restrict__ WqT,
                                              u16* __restrict__ WkT,
                                              u16* __restrict__ WvT,
                                              u16* __restrict__ Wob, int H) {
    __shared__ float t[32][33];
    const int z = blockIdx.z;
    const float* in = (z == 0) ? Wk : (z == 1) ? Wq : (z == 2) ? Wv : Wo;
    u16* out = (z == 0) ? WkT : (z == 1) ? WqT : (z == 2) ? WvT : Wob;
    int bx = blockIdx.x * 32, by = blockIdx.y * 32;
    int x = threadIdx.x;
    if (z < 3) {
        for (int y = threadIdx.y; y < 32; y += 8)
            t[y][x] = in[(size_t)(by + y) * H + bx + x];
        __syncthreads();
        for (int y = threadIdx.y; y < 32; y += 8)
            out[(size_t)(bx + y) * H + by + x] = f2bf(t[x][y]);
    } else {
        for (int y = threadIdx.y; y < 32; y += 8)
            out[(size_t)(by + y) * H + bx + x] = f2bf(in[(size_t)(by + y) * H + bx + x]);
    }
}

// uk[h] = sum_o Wk[o,h]*bq[o]; grid (H/256, 16); u zeroed first.
__global__ __launch_bounds__(256) void k_uk(const float* __restrict__ Wk,
                                            const float* __restrict__ bq,
                                            float* __restrict__ u, int H) {
    int h = blockIdx.x * 256 + threadIdx.x;
    int chunk = H / 16;
    int o0 = blockIdx.y * chunk;
    float s = 0.f;
    for (int o = o0; o < o0 + chunk; ++o) s += bq[o] * Wk[(size_t)o * H + h];
    atomicAdd(&u[h], s);
}

// c[j] = sum_o Wo[j,o]*bv[o] + bo[j]
__global__ __launch_bounds__(256) void k_bias(const float* __restrict__ Wo,
                                              const float* __restrict__ bv,
                                              const float* __restrict__ bo,
                                              float* __restrict__ c, int H) {
    __shared__ float red[4];
    int j = blockIdx.x;
    int lane = threadIdx.x & 63, wv = threadIdx.x >> 6;
    float s = 0.f;
    for (int o = threadIdx.x; o < H; o += 256) s += Wo[(size_t)j * H + o] * bv[o];
    for (int off = 32; off > 0; off >>= 1) s += __shfl_down(s, off);
    if (lane == 0) red[wv] = s;
    __syncthreads();
    if (threadIdx.x == 0) c[j] = red[0] + red[1] + red[2] + red[3] + bo[j];
}

// ---------------------------------------------------------------------------
// bf16 BT-GEMM body (R2-verified, byte-for-byte). C[i,j] = sum_k A[i,k]*Bw[j,k]
// (+bias[j] if bias != null). OUTB=1: bf16 out; OUTB=0: fp32 out.
template <int OUTB>
__device__ __forceinline__ void gemm_body(const u16* __restrict__ A,
                                          const u16* __restrict__ Bw,
                                          void* __restrict__ Cp,
                                          const float* __restrict__ bias,
                                          int M, int N, int K,
                                          int bx, int by) {
    __shared__ __align__(16) u16 As[128 * 32];
    __shared__ __align__(16) u16 Bs[128 * 32];
    const int tid = threadIdx.x, lane = tid & 63, wv = tid >> 6;
    const int m0 = bx * 128, n0 = by * 128;
    const int wm = (wv >> 1) * 64, wn = (wv & 1) * 64;

    floatx4 acc[4][4];
#pragma unroll
    for (int i = 0; i < 4; ++i)
#pragma unroll
        for (int j = 0; j < 4; ++j) acc[i][j] = (floatx4){0.f, 0.f, 0.f, 0.f};

    const int srow = lane >> 2;
    const int scol = (((lane & 3) ^ ((lane >> 3) & 3)) * 8);
    const u16* gA = A + (size_t)(m0 + srow) * K + scol;
    const u16* gB = Bw + (size_t)(n0 + srow) * K + scol;
    const int r = lane & 15, q = lane >> 4;
    const int cph = q ^ ((r >> 1) & 3);

    for (int kt = 0; kt < K; kt += 32) {
#pragma unroll
        for (int c = 0; c < 2; ++c) {
            int chunk = wv * 2 + c;
            load_lds16(gA + (size_t)(chunk * 16) * K + kt, &As[chunk * 16 * 32]);
            load_lds16(gB + (size_t)(chunk * 16) * K + kt, &Bs[chunk * 16 * 32]);
        }
        __syncthreads();
        bf16x8 af[4], bfr[4];
#pragma unroll
        for (int i = 0; i < 4; ++i) {
            af[i] = *(const bf16x8*)&As[(wm + i * 16 + r) * 32 + cph * 8];
            bfr[i] = *(const bf16x8*)&Bs[(wn + i * 16 + r) * 32 + cph * 8];
        }
#pragma unroll
        for (int i = 0; i < 4; ++i)
#pragma unroll
            for (int j = 0; j < 4; ++j)
                acc[i][j] = __builtin_amdgcn_mfma_f32_16x16x32_bf16(af[i], bfr[j], acc[i][j], 0, 0, 0);
        __syncthreads();
    }

    const int cc = lane & 15, cr = (lane >> 4) * 4;
#pragma unroll
    for (int i = 0; i < 4; ++i)
#pragma unroll
        for (int j = 0; j < 4; ++j) {
            int col = n0 + wn + j * 16 + cc;
            float badd = bias ? bias[col] : 0.f;
#pragma unroll
            for (int r0 = 0; r0 < 4; ++r0) {
                int row = m0 + wm + i * 16 + cr + r0;
                float v = acc[i][j][r0] + badd;
                if (OUTB) ((u16*)Cp)[(size_t)row * N + col] = f2bf(v);
                else ((float*)Cp)[(size_t)row * N + col] = v;
            }
        }
}

// weight GEMMs (one launch): z=0: Aw = bf16(Wk^T Wq); z=1: Wov = bf16(Wo Wv)
__global__ __launch_bounds__(256) void k_wgemm(const u16* __restrict__ A0,
                                               const u16* __restrict__ B0,
                                               u16* __restrict__ C0,
                                               const u16* __restrict__ A1,
                                               const u16* __restrict__ B1,
                                               u16* __restrict__ C1, int H) {
    if (blockIdx.z == 0)
        gemm_body<1>(A0, B0, C0, nullptr, H, H, H, blockIdx.x, blockIdx.y);
    else
        gemm_body<1>(A1, B1, C1, nullptr, H, H, H, blockIdx.x, blockIdx.y);
}

// score GEMM: G[r,h'] = sum_h X[r,h]*Aw[h',h] + uk[h'], bf16 out
__global__ __launch_bounds__(256) void k_score(const u16* __restrict__ X,
                                               const u16* __restrict__ Aw,
                                               u16* __restrict__ G,
                                               const float* __restrict__ uk,
                                               int Mr, int N, int K) {
    gemm_body<1>(X, Aw, G, uk, Mr, N, K, blockIdx.x, blockIdx.y);
}

// out = Y @ Wov^T + cvec (fp32 out)
__global__ __launch_bounds__(256) void k_out(const u16* __restrict__ A,
                                             const u16* __restrict__ Bw,
                                             float* __restrict__ C,
                                             const float* __restrict__ bias,
                                             int M, int N, int K) {
    gemm_body<0>(A, Bw, C, bias, M, N, K, blockIdx.x, blockIdx.y);
}

// ---------------------------------------------------------------------------
// Per-batch attention, one wave per batch; X retained in registers.
// s[m][n] = G_m . X_n ; row-constant score terms cancel in softmax over n.
__global__ __launch_bounds__(256) void k_attn(const u16* __restrict__ G,
                                              const u16* __restrict__ X,
                                              const float* __restrict__ conf,
                                              u16* __restrict__ Y, int H) {
    const int lane = threadIdx.x & 63, wv = threadIdx.x >> 6;
    const int b = blockIdx.x * 4 + wv;
    const u16* Gb = G + (size_t)b * 4 * H;
    const u16* Xb = X + (size_t)b * 4 * H;

    uint4 xraw[2][4];
    float s[16];
#pragma unroll
    for (int t = 0; t < 16; ++t) s[t] = 0.f;

#pragma unroll
    for (int c = 0; c < 2; ++c) {
        const int off = c * 512 + lane * 8;
#pragma unroll
        for (int rr = 0; rr < 4; ++rr)
            xraw[c][rr] = *(const uint4*)(Xb + rr * H + off);
        float xv[4][8];
#pragma unroll
        for (int rr = 0; rr < 4; ++rr) unpack8(xraw[c][rr], xv[rr]);
#pragma unroll
        for (int m = 0; m < 4; ++m) {
            uint4 gl = *(const uint4*)(Gb + m * H + off);
            float gv[8];
            unpack8(gl, gv);
#pragma unroll
            for (int n = 0; n < 4; ++n) {
                float a = 0.f;
#pragma unroll
                for (int j = 0; j < 8; ++j) a += gv[j] * xv[n][j];
                s[m * 4 + n] += a;
            }
        }
    }
#pragma unroll
    for (int t = 0; t < 16; ++t) {
#pragma unroll
        for (int mask = 32; mask; mask >>= 1) s[t] += __shfl_xor(s[t], mask);
    }
    float w[4] = {0.f, 0.f, 0.f, 0.f};
#pragma unroll
    for (int m = 0; m < 4; ++m) {
        float cm = conf[(size_t)b * 4 + m] * 0.03125f;  // 1/sqrt(1024)
        float sc[4], mx = -1e30f;
#pragma unroll
        for (int n = 0; n < 4; ++n) {
            sc[n] = s[m * 4 + n] * cm;
            mx = fmaxf(mx, sc[n]);
        }
        float e[4], ssum = 0.f;
#pragma unroll
        for (int n = 0; n < 4; ++n) { e[n] = __expf(sc[n] - mx); ssum += e[n]; }
        float inv = 0.25f / ssum;
#pragma unroll
        for (int n = 0; n < 4; ++n) w[n] += e[n] * inv;
    }
#pragma unroll
    for (int c = 0; c < 2; ++c) {
        const int off = c * 512 + lane * 8;
        float xv[4][8];
#pragma unroll
        for (int rr = 0; rr < 4; ++rr) unpack8(xraw[c][rr], xv[rr]);
        float y[8];
#pragma unroll
        for (int j = 0; j < 8; ++j)
            y[j] = w[0] * xv[0][j] + w[1] * xv[1][j] + w[2] * xv[2][j] + w[3] * xv[3][j];
        uint4 res;
        res.x = (unsigned)f2bf(y[0]) | ((unsigned)f2bf(y[1]) << 16);
        res.y = (unsigned)f2bf(y[2]) | ((unsigned)f2bf(y[3]) << 16);
        res.z = (unsigned)f2bf(y[4]) | ((unsigned)f2bf(y[5]) << 16);
        res.w = (unsigned)f2bf(y[6]) | ((unsigned)f2bf(y[7]) << 16);
        *(uint4*)(Y + (size_t)b * H + off) = res;
    }
}

// ---------------------------------------------------------------------------
extern "C" void kernel_launch(void* const* d_in, const int* in_sizes, int n_in,
                              void* d_out, int out_size, void* d_ws, size_t ws_size,
                              hipStream_t stream) {
    const int H = 1024, M = 4;
    const int B = in_sizes[0] / (H * M);
    const long BMH = (long)B * M * H;

    const float* feat = (const float*)d_in[0];
    const float* conf = (const float*)d_in[1];
    const float* Wq = (const float*)d_in[2];
    const float* bq = (const float*)d_in[3];
    const float* Wk = (const float*)d_in[4];
    const float* Wv = (const float*)d_in[6];
    const float* bv = (const float*)d_in[7];
    const float* Wo = (const float*)d_in[8];
    const float* bo = (const float*)d_in[9];

    char* ws = (char*)d_ws;
    size_t off = 0;
    auto alloc = [&](size_t bytes) {
        void* p = ws + off;
        off += (bytes + 255) & ~(size_t)255;
        return p;
    };
    u16* Xb    = (u16*)alloc((size_t)BMH * 2);   //  64 MB
    u16* G     = (u16*)alloc((size_t)BMH * 2);   //  64 MB
    u16* Yb    = (u16*)alloc((size_t)B * H * 2); //  16 MB
    u16* WkT   = (u16*)alloc((size_t)H * H * 2); //   2 MB each below
    u16* WqT   = (u16*)alloc((size_t)H * H * 2);
    u16* WvT   = (u16*)alloc((size_t)H * H * 2);
    u16* Wob   = (u16*)alloc((size_t)H * H * 2);
    u16* Aw    = (u16*)alloc((size_t)H * H * 2);
    u16* Wov   = (u16*)alloc((size_t)H * H * 2);
    float* u    = (float*)alloc((size_t)H * 4);
    float* cvec = (float*)alloc((size_t)H * 4);
    (void)ws_size; (void)n_in; (void)out_size;       // total ~156 MB (= R2)

    // 1. feature cast and weight prep
    k_cast<<<(int)(BMH / 4 / 256), 256, 0, stream>>>(feat, Xb, BMH);
    k_prep<<<dim3(H / 32, H / 32, 4), dim3(32, 8), 0, stream>>>(
        Wq, Wk, Wv, Wo, WqT, WkT, WvT, Wob, H);

    // 2. bias-derived vectors
    hipMemsetAsync(u, 0, (size_t)H * 4, stream);
    k_uk<<<dim3(H / 256, 16), 256, 0, stream>>>(Wk, bq, u, H);
    k_bias<<<H, 256, 0, stream>>>(Wo, bv, bo, cvec, H);

    // 3. weight GEMMs: Aw = Wk^T Wq ; Wov = Wo Wv
    k_wgemm<<<dim3(H / 128, H / 128, 2), 256, 0, stream>>>(
        WkT, WqT, Aw, Wob, WvT, Wov, H);

    // 4. score GEMM: G = bf16(X Aw^T + uk)
    k_score<<<dim3(B * M / 128, H / 128), 256, 0, stream>>>(
        Xb, Aw, G, u, B * M, H, H);

    // 5. attention -> Y
    k_attn<<<B / 4, 256, 0, stream>>>(G, Xb, conf, Yb, H);

    // 6. out = Y @ Wov^T + cvec
    k_out<<<dim3(B / 128, H / 128), 256, 0, stream>>>(Yb, Wov, (float*)d_out, cvec, B, H, H);
}

// Round 6
// 415.675 us; speedup vs baseline: 1.1897x; 1.0029x over previous
//
#include <hip/hip_runtime.h>

// WS layout: base (R5-proven) ~156 MB; fp8 extras Xf8+Awf8 +33 MB appended.
// Host guards on ws_size: if extras don't fit, fall back to bf16 score path.

typedef unsigned short u16;
typedef unsigned char u8;
typedef __attribute__((ext_vector_type(8))) __bf16 bf16x8;
typedef __attribute__((ext_vector_type(4))) float floatx4;

__device__ __forceinline__ u16 f2bf(float f) {
    unsigned u = __float_as_uint(f);
    unsigned r = (u + 0x7FFFu + ((u >> 16) & 1u)) >> 16;
    return (u16)r;
}

// float -> OCP e4m3fn, RNE, saturate. Layout [s:1][e:4][m:3]: exp at BIT 3.
// (R3/R4 bug: used ex<<4, smashing exponent into the sign bit.)
__device__ __forceinline__ unsigned f2e4m3(float x) {
    unsigned u = __float_as_uint(x);
    unsigned s = (u >> 31) << 7;
    float a = __uint_as_float(u & 0x7FFFFFFFu);
    if (a >= 448.f) return s | 0x7E;
    if (a < 0.03125f) {  // codes 0..16 are exactly k * 2^-9
        unsigned k = (unsigned)__float2int_rn(a * 512.f);
        return s | k;
    }
    unsigned b = __float_as_uint(a);
    unsigned lsb = (b >> 20) & 1u;
    b += 0x0007FFFFu + lsb;  // RNE to 3 mantissa bits (carry fixes exponent)
    unsigned ex = (b >> 23) - 120u;      // fp32 bias 127 -> e4m3 bias 7
    unsigned man = (b >> 20) & 7u;
    return s | (ex << 3) | man;
}

__device__ __forceinline__ void load_lds16(const void* g, void* l) {
    __builtin_amdgcn_global_load_lds(
        (const __attribute__((address_space(1))) void*)g,
        (__attribute__((address_space(3))) void*)l, 16, 0, 0);
}

__device__ __forceinline__ void unpack8(uint4 v, float* f) {
    f[0] = __uint_as_float(v.x << 16);
    f[1] = __uint_as_float(v.x & 0xFFFF0000u);
    f[2] = __uint_as_float(v.y << 16);
    f[3] = __uint_as_float(v.y & 0xFFFF0000u);
    f[4] = __uint_as_float(v.z << 16);
    f[5] = __uint_as_float(v.z & 0xFFFF0000u);
    f[6] = __uint_as_float(v.w << 16);
    f[7] = __uint_as_float(v.w & 0xFFFF0000u);
}

// ---------------------------------------------------------------------------
// features fp32 -> bf16 (+fp8 if outf != null); 4 els/thread
__global__ __launch_bounds__(256) void k_cast(const float* __restrict__ in,
                                              u16* __restrict__ outb,
                                              u8* __restrict__ outf, long n) {
    long i = ((long)blockIdx.x * 256 + threadIdx.x) * 4;
    if (i < n) {
        float4 v = *(const float4*)(in + i);
        ushort4 o;
        o.x = f2bf(v.x); o.y = f2bf(v.y); o.z = f2bf(v.z); o.w = f2bf(v.w);
        *(ushort4*)(outb + i) = o;
        if (outf) {
            unsigned p = f2e4m3(v.x) | (f2e4m3(v.y) << 8) |
                         (f2e4m3(v.z) << 16) | (f2e4m3(v.w) << 24);
            *(unsigned*)(outf + i) = p;
        }
    }
}

// z=0: WkT=Wk^T, z=1: WqT=Wq^T, z=2: WvT=Wv^T (transpose+cast); z=3: Wob=cast(Wo)
__global__ __launch_bounds__(256) void k_prep(const float* __restrict__ Wq,
                                              const float* __restrict__ Wk,
                                              const float* __restrict__ Wv,
                                              const float* __restrict__ Wo,
                                              u16* __restrict__ WqT,
                                              u16* __restrict__ WkT,
                                              u16* __restrict__ WvT,
                                              u16* __restrict__ Wob, int H) {
    __shared__ float t[32][33];
    const int z = blockIdx.z;
    const float* in = (z == 0) ? Wk : (z == 1) ? Wq : (z == 2) ? Wv : Wo;
    u16* out = (z == 0) ? WkT : (z == 1) ? WqT : (z == 2) ? WvT : Wob;
    int bx = blockIdx.x * 32, by = blockIdx.y * 32;
    int x = threadIdx.x;
    if (z < 3) {
        for (int y = threadIdx.y; y < 32; y += 8)
            t[y][x] = in[(size_t)(by + y) * H + bx + x];
        __syncthreads();
        for (int y = threadIdx.y; y < 32; y += 8)
            out[(size_t)(bx + y) * H + by + x] = f2bf(t[x][y]);
    } else {
        for (int y = threadIdx.y; y < 32; y += 8)
            out[(size_t)(by + y) * H + bx + x] = f2bf(in[(size_t)(by + y) * H + bx + x]);
    }
}

// uk[h] = sum_o Wk[o,h]*bq[o]; grid (H/256, 16); u zeroed first.
__global__ __launch_bounds__(256) void k_uk(const float* __restrict__ Wk,
                                            const float* __restrict__ bq,
                                            float* __restrict__ u, int H) {
    int h = blockIdx.x * 256 + threadIdx.x;
    int chunk = H / 16;
    int o0 = blockIdx.y * chunk;
    float s = 0.f;
    for (int o = o0; o < o0 + chunk; ++o) s += bq[o] * Wk[(size_t)o * H + h];
    atomicAdd(&u[h], s);
}

// c[j] = sum_o Wo[j,o]*bv[o] + bo[j]
__global__ __launch_bounds__(256) void k_bias(const float* __restrict__ Wo,
                                              const float* __restrict__ bv,
                                              const float* __restrict__ bo,
                                              float* __restrict__ c, int H) {
    __shared__ float red[4];
    int j = blockIdx.x;
    int lane = threadIdx.x & 63, wv = threadIdx.x >> 6;
    float s = 0.f;
    for (int o = threadIdx.x; o < H; o += 256) s += Wo[(size_t)j * H + o] * bv[o];
    for (int off = 32; off > 0; off >>= 1) s += __shfl_down(s, off);
    if (lane == 0) red[wv] = s;
    __syncthreads();
    if (threadIdx.x == 0) c[j] = red[0] + red[1] + red[2] + red[3] + bo[j];
}

// ---------------------------------------------------------------------------
// bf16 BT-GEMM body (R2/R5-verified). OUTMODE 0: fp32+bias; 1: bf16(+bias);
// 2: dual-write bf16 (Cp) AND fp8(32x) (Cp8).
template <int OUTMODE>
__device__ __forceinline__ void gemm_body(const u16* __restrict__ A,
                                          const u16* __restrict__ Bw,
                                          void* __restrict__ Cp,
                                          u8* __restrict__ Cp8,
                                          const float* __restrict__ bias,
                                          int M, int N, int K,
                                          int bx, int by) {
    __shared__ __align__(16) u16 As[128 * 32];
    __shared__ __align__(16) u16 Bs[128 * 32];
    const int tid = threadIdx.x, lane = tid & 63, wv = tid >> 6;
    const int m0 = bx * 128, n0 = by * 128;
    const int wm = (wv >> 1) * 64, wn = (wv & 1) * 64;

    floatx4 acc[4][4];
#pragma unroll
    for (int i = 0; i < 4; ++i)
#pragma unroll
        for (int j = 0; j < 4; ++j) acc[i][j] = (floatx4){0.f, 0.f, 0.f, 0.f};

    const int srow = lane >> 2;
    const int scol = (((lane & 3) ^ ((lane >> 3) & 3)) * 8);
    const u16* gA = A + (size_t)(m0 + srow) * K + scol;
    const u16* gB = Bw + (size_t)(n0 + srow) * K + scol;
    const int r = lane & 15, q = lane >> 4;
    const int cph = q ^ ((r >> 1) & 3);

    for (int kt = 0; kt < K; kt += 32) {
#pragma unroll
        for (int c = 0; c < 2; ++c) {
            int chunk = wv * 2 + c;
            load_lds16(gA + (size_t)(chunk * 16) * K + kt, &As[chunk * 16 * 32]);
            load_lds16(gB + (size_t)(chunk * 16) * K + kt, &Bs[chunk * 16 * 32]);
        }
        __syncthreads();
        bf16x8 af[4], bfr[4];
#pragma unroll
        for (int i = 0; i < 4; ++i) {
            af[i] = *(const bf16x8*)&As[(wm + i * 16 + r) * 32 + cph * 8];
            bfr[i] = *(const bf16x8*)&Bs[(wn + i * 16 + r) * 32 + cph * 8];
        }
#pragma unroll
        for (int i = 0; i < 4; ++i)
#pragma unroll
            for (int j = 0; j < 4; ++j)
                acc[i][j] = __builtin_amdgcn_mfma_f32_16x16x32_bf16(af[i], bfr[j], acc[i][j], 0, 0, 0);
        __syncthreads();
    }

    const int cc = lane & 15, cr = (lane >> 4) * 4;
#pragma unroll
    for (int i = 0; i < 4; ++i)
#pragma unroll
        for (int j = 0; j < 4; ++j) {
            int col = n0 + wn + j * 16 + cc;
            float badd = bias ? bias[col] : 0.f;
#pragma unroll
            for (int r0 = 0; r0 < 4; ++r0) {
                int row = m0 + wm + i * 16 + cr + r0;
                float v = acc[i][j][r0] + badd;
                if (OUTMODE == 0) ((float*)Cp)[(size_t)row * N + col] = v;
                else ((u16*)Cp)[(size_t)row * N + col] = f2bf(v);
                if (OUTMODE == 2)
                    Cp8[(size_t)row * N + col] = (u8)f2e4m3(32.f * v);
            }
        }
}

// weight GEMMs (one launch): z=0: Aw=bf16(Wk^T Wq) + Awf8=fp8(32x); z=1: Wov
__global__ __launch_bounds__(256) void k_wgemm(const u16* __restrict__ A0,
                                               const u16* __restrict__ B0,
                                               u16* __restrict__ C0,
                                               u8* __restrict__ C0f8,
                                               const u16* __restrict__ A1,
                                               const u16* __restrict__ B1,
                                               u16* __restrict__ C1, int H) {
    if (blockIdx.z == 0)
        gemm_body<2>(A0, B0, C0, C0f8, nullptr, H, H, H, blockIdx.x, blockIdx.y);
    else
        gemm_body<1>(A1, B1, C1, nullptr, nullptr, H, H, H, blockIdx.x, blockIdx.y);
}

// bf16 fallback score GEMM: G = bf16(X Aw^T + uk)
__global__ __launch_bounds__(256) void k_score(const u16* __restrict__ X,
                                               const u16* __restrict__ Aw,
                                               u16* __restrict__ G,
                                               const float* __restrict__ uk,
                                               int Mr, int N, int K) {
    gemm_body<1>(X, Aw, G, nullptr, uk, Mr, N, K, blockIdx.x, blockIdx.y);
}

// out = Y @ Wov^T + cvec (fp32 out)
__global__ __launch_bounds__(256) void k_out(const u16* __restrict__ A,
                                             const u16* __restrict__ Bw,
                                             float* __restrict__ C,
                                             const float* __restrict__ bias,
                                             int M, int N, int K) {
    gemm_body<0>(A, Bw, C, nullptr, bias, M, N, K, blockIdx.x, blockIdx.y);
}

// ---------------------------------------------------------------------------
// fp8 score GEMM via mfma_f32_16x16x32_fp8_fp8 (i64 frags; bf16-family layout
// m=lane&15, k=(lane>>4)*8+byte; C/D dtype-independent). BK=64 bytes.
// G[r,h'] = 32*(sum_h X[r,h]*Aw[h',h] + uk[h']), bf16 out.
// grid (N/128, Mr/128): x-adjacent blocks share the A-row-panel (L2 reuse).
__global__ __launch_bounds__(256) void k_score8(const u8* __restrict__ Af8,
                                                const u8* __restrict__ Bf8,
                                                u16* __restrict__ G,
                                                const float* __restrict__ uk,
                                                int Mr, int N, int K) {
    __shared__ __align__(16) u8 As[128 * 64];
    __shared__ __align__(16) u8 Bs[128 * 64];
    const int tid = threadIdx.x, lane = tid & 63, wv = tid >> 6;
    const int n0 = blockIdx.x * 128, m0 = blockIdx.y * 128;
    const int wm = (wv >> 1) * 64, wn = (wv & 1) * 64;

    floatx4 acc[4][4];
#pragma unroll
    for (int i = 0; i < 4; ++i)
#pragma unroll
        for (int j = 0; j < 4; ++j) acc[i][j] = (floatx4){0.f, 0.f, 0.f, 0.f};

    const int srow = lane >> 2;
    const int scol = 16 * ((lane & 3) ^ ((lane >> 3) & 3));
    const u8* gA = Af8 + (size_t)(m0 + srow) * K + scol;
    const u8* gB = Bf8 + (size_t)(n0 + srow) * K + scol;
    const int r = lane & 15, q = lane >> 4;
    const int swz = (r >> 1) & 3;
    const int qh = q >> 1, ql = (q & 1) * 8;

    for (int kt = 0; kt < K; kt += 64) {
#pragma unroll
        for (int c = 0; c < 2; ++c) {
            int chunk = wv * 2 + c;
            load_lds16(gA + (size_t)(chunk * 16) * K + kt, &As[chunk * 16 * 64]);
            load_lds16(gB + (size_t)(chunk * 16) * K + kt, &Bs[chunk * 16 * 64]);
        }
        __syncthreads();
#pragma unroll
        for (int s = 0; s < 2; ++s) {  // two K=32 MFMA steps per 64-B tile
            long long af[4], bfr[4];
#pragma unroll
            for (int i = 0; i < 4; ++i) {
                int piece = ((2 * s + qh) ^ swz) * 16 + ql;
                af[i] = *(const long long*)&As[(wm + i * 16 + r) * 64 + piece];
                bfr[i] = *(const long long*)&Bs[(wn + i * 16 + r) * 64 + piece];
            }
#pragma unroll
            for (int i = 0; i < 4; ++i)
#pragma unroll
                for (int j = 0; j < 4; ++j)
                    acc[i][j] = __builtin_amdgcn_mfma_f32_16x16x32_fp8_fp8(
                        af[i], bfr[j], acc[i][j], 0, 0, 0);
        }
        __syncthreads();
    }

    const int cc = lane & 15, cr = (lane >> 4) * 4;
#pragma unroll
    for (int i = 0; i < 4; ++i)
#pragma unroll
        for (int j = 0; j < 4; ++j) {
            int col = n0 + wn + j * 16 + cc;
            float badd = 32.f * uk[col];
#pragma unroll
            for (int r0 = 0; r0 < 4; ++r0) {
                int row = m0 + wm + i * 16 + cr + r0;
                G[(size_t)row * N + col] = f2bf(acc[i][j][r0] + badd);
            }
        }
}

// ---------------------------------------------------------------------------
// Per-batch attention, one wave per batch; X retained in registers.
// gscale folds G's scale into the softmax: bf16 G -> conf/32; fp8 G -> conf/1024.
__global__ __launch_bounds__(256) void k_attn(const u16* __restrict__ G,
                                              const u16* __restrict__ X,
                                              const float* __restrict__ conf,
                                              u16* __restrict__ Y, float gscale,
                                              int H) {
    const int lane = threadIdx.x & 63, wv = threadIdx.x >> 6;
    const int b = blockIdx.x * 4 + wv;
    const u16* Gb = G + (size_t)b * 4 * H;
    const u16* Xb = X + (size_t)b * 4 * H;

    uint4 xraw[2][4];
    float s[16];
#pragma unroll
    for (int t = 0; t < 16; ++t) s[t] = 0.f;

#pragma unroll
    for (int c = 0; c < 2; ++c) {
        const int off = c * 512 + lane * 8;
#pragma unroll
        for (int rr = 0; rr < 4; ++rr)
            xraw[c][rr] = *(const uint4*)(Xb + rr * H + off);
        float xv[4][8];
#pragma unroll
        for (int rr = 0; rr < 4; ++rr) unpack8(xraw[c][rr], xv[rr]);
#pragma unroll
        for (int m = 0; m < 4; ++m) {
            uint4 gl = *(const uint4*)(Gb + m * H + off);
            float gv[8];
            unpack8(gl, gv);
#pragma unroll
            for (int n = 0; n < 4; ++n) {
                float a = 0.f;
#pragma unroll
                for (int j = 0; j < 8; ++j) a += gv[j] * xv[n][j];
                s[m * 4 + n] += a;
            }
        }
    }
#pragma unroll
    for (int t = 0; t < 16; ++t) {
#pragma unroll
        for (int mask = 32; mask; mask >>= 1) s[t] += __shfl_xor(s[t], mask);
    }
    float w[4] = {0.f, 0.f, 0.f, 0.f};
#pragma unroll
    for (int m = 0; m < 4; ++m) {
        float cm = conf[(size_t)b * 4 + m] * gscale;
        float sc[4], mx = -1e30f;
#pragma unroll
        for (int n = 0; n < 4; ++n) {
            sc[n] = s[m * 4 + n] * cm;
            mx = fmaxf(mx, sc[n]);
        }
        float e[4], ssum = 0.f;
#pragma unroll
        for (int n = 0; n < 4; ++n) { e[n] = __expf(sc[n] - mx); ssum += e[n]; }
        float inv = 0.25f / ssum;
#pragma unroll
        for (int n = 0; n < 4; ++n) w[n] += e[n] * inv;
    }
#pragma unroll
    for (int c = 0; c < 2; ++c) {
        const int off = c * 512 + lane * 8;
        float xv[4][8];
#pragma unroll
        for (int rr = 0; rr < 4; ++rr) unpack8(xraw[c][rr], xv[rr]);
        float y[8];
#pragma unroll
        for (int j = 0; j < 8; ++j)
            y[j] = w[0] * xv[0][j] + w[1] * xv[1][j] + w[2] * xv[2][j] + w[3] * xv[3][j];
        uint4 res;
        res.x = (unsigned)f2bf(y[0]) | ((unsigned)f2bf(y[1]) << 16);
        res.y = (unsigned)f2bf(y[2]) | ((unsigned)f2bf(y[3]) << 16);
        res.z = (unsigned)f2bf(y[4]) | ((unsigned)f2bf(y[5]) << 16);
        res.w = (unsigned)f2bf(y[6]) | ((unsigned)f2bf(y[7]) << 16);
        *(uint4*)(Y + (size_t)b * H + off) = res;
    }
}

// ---------------------------------------------------------------------------
extern "C" void kernel_launch(void* const* d_in, const int* in_sizes, int n_in,
                              void* d_out, int out_size, void* d_ws, size_t ws_size,
                              hipStream_t stream) {
    const int H = 1024, M = 4;
    const int B = in_sizes[0] / (H * M);
    const long BMH = (long)B * M * H;

    const float* feat = (const float*)d_in[0];
    const float* conf = (const float*)d_in[1];
    const float* Wq = (const float*)d_in[2];
    const float* bq = (const float*)d_in[3];
    const float* Wk = (const float*)d_in[4];
    const float* Wv = (const float*)d_in[6];
    const float* bv = (const float*)d_in[7];
    const float* Wo = (const float*)d_in[8];
    const float* bo = (const float*)d_in[9];

    char* ws = (char*)d_ws;
    size_t off = 0;
    auto alloc = [&](size_t bytes) {
        void* p = ws + off;
        off += (bytes + 255) & ~(size_t)255;
        return p;
    };
    // base (R5-proven footprint)
    u16* Xb    = (u16*)alloc((size_t)BMH * 2);   //  64 MB
    u16* G     = (u16*)alloc((size_t)BMH * 2);   //  64 MB
    u16* Yb    = (u16*)alloc((size_t)B * H * 2); //  16 MB
    u16* WkT   = (u16*)alloc((size_t)H * H * 2);
    u16* WqT   = (u16*)alloc((size_t)H * H * 2);
    u16* WvT   = (u16*)alloc((size_t)H * H * 2);
    u16* Wob   = (u16*)alloc((size_t)H * H * 2);
    u16* Aw    = (u16*)alloc((size_t)H * H * 2);
    u16* Wov   = (u16*)alloc((size_t)H * H * 2);
    float* u    = (float*)alloc((size_t)H * 4);
    float* cvec = (float*)alloc((size_t)H * 4);
    // fp8 extras (+33 MB) — only used if they fit
    u8* Xf8  = (u8*)alloc((size_t)BMH);
    u8* Awf8 = (u8*)alloc((size_t)H * H);
    const bool use_fp8 = (off <= ws_size);
    (void)n_in; (void)out_size;

    // 1. feature cast and weight prep
    k_cast<<<(int)(BMH / 4 / 256), 256, 0, stream>>>(
        feat, Xb, use_fp8 ? Xf8 : nullptr, BMH);
    k_prep<<<dim3(H / 32, H / 32, 4), dim3(32, 8), 0, stream>>>(
        Wq, Wk, Wv, Wo, WqT, WkT, WvT, Wob, H);

    // 2. bias-derived vectors
    hipMemsetAsync(u, 0, (size_t)H * 4, stream);
    k_uk<<<dim3(H / 256, 16), 256, 0, stream>>>(Wk, bq, u, H);
    k_bias<<<H, 256, 0, stream>>>(Wo, bv, bo, cvec, H);

    // 3. weight GEMMs: Aw (bf16 + fp8x32) = Wk^T Wq ; Wov = Wo Wv
    k_wgemm<<<dim3(H / 128, H / 128, 2), 256, 0, stream>>>(
        WkT, WqT, Aw, use_fp8 ? Awf8 : (u8*)Aw /*unused*/, Wob, WvT, Wov, H);

    // 4. score GEMM
    if (use_fp8) {
        k_score8<<<dim3(H / 128, B * M / 128), 256, 0, stream>>>(
            Xf8, Awf8, G, u, B * M, H, H);
    } else {
        k_score<<<dim3(B * M / 128, H / 128), 256, 0, stream>>>(
            Xb, Aw, G, u, B * M, H, H);
    }

    // 5. attention -> Y  (fp8 G carries a 32x scale: 1/(32*32) vs 1/32)
    k_attn<<<B / 4, 256, 0, stream>>>(G, Xb, conf, Yb,
                                      use_fp8 ? 0.0009765625f : 0.03125f, H);

    // 6. out = Y @ Wov^T + cvec
    k_out<<<dim3(B / 128, H / 128), 256, 0, stream>>>(Yb, Wov, (float*)d_out, cvec, B, H, H);
}